// Round 1
// baseline (389.699 us; speedup 1.0000x reference)
//
#include <hip/hip_runtime.h>
#include <math.h>

#define NB 32
#define C 256
#define H 64
#define W 64
#define HW 4096

// ---------------------------------------------------------------------------
// K1: per-(n,c) global max of relu(x) -> t3   [+ one extra block computes
//     w2bar[c] = mean_o W2[o,c] ]
// ---------------------------------------------------------------------------
__global__ __launch_bounds__(256) void k1_t3_prep(
    const float* __restrict__ x, const float* __restrict__ W2,
    float* __restrict__ w2bar, float* __restrict__ t3) {
  int b = blockIdx.x;
  int tid = threadIdx.x;
  if (b == NB * C) {
    // prep block: column means of W2 (coalesced over c)
    float s = 0.f;
    for (int o = 0; o < C; ++o) s += W2[o * C + tid];
    w2bar[tid] = s * (1.0f / (float)C);
    return;
  }
  const float4* xv = (const float4*)(x + (size_t)b * HW);
  float m = -3.4e38f;
#pragma unroll
  for (int i = 0; i < 4; ++i) {
    float4 v = xv[i * 256 + tid];
    m = fmaxf(m, fmaxf(fmaxf(v.x, v.y), fmaxf(v.z, v.w)));
  }
  // wave64 reduce
  for (int off = 32; off > 0; off >>= 1)
    m = fmaxf(m, __shfl_down(m, off, 64));
  __shared__ float sm[4];
  if ((tid & 63) == 0) sm[tid >> 6] = m;
  __syncthreads();
  if (tid == 0) {
    float mm = fmaxf(fmaxf(sm[0], sm[1]), fmaxf(sm[2], sm[3]));
    t3[b] = fmaxf(mm, 0.0f);  // relu then max == max then clamp
  }
}

// ---------------------------------------------------------------------------
// K2: one streaming pass over x. Per pixel p of image n:
//   s   = sum_c w2bar[c]*relu(x)   -> t5  = p4 * s
//   t9  = sum_c t3[n,c]*x          -> t13 = p13 * t9
// ---------------------------------------------------------------------------
__global__ __launch_bounds__(256) void k2_s_t9(
    const float* __restrict__ x, const float* __restrict__ w2bar,
    const float* __restrict__ t3, const float* __restrict__ p4,
    const float* __restrict__ p13, float* __restrict__ t5,
    float* __restrict__ t13) {
  int n = blockIdx.x >> 4;
  int p = ((blockIdx.x & 15) << 8) | threadIdx.x;
  __shared__ float sw[C];
  __shared__ float st[C];
  sw[threadIdx.x] = w2bar[threadIdx.x];
  st[threadIdx.x] = t3[n * C + threadIdx.x];
  __syncthreads();
  const float* xp = x + (size_t)n * C * HW + p;
  float accs = 0.f, acc9 = 0.f;
#pragma unroll 16
  for (int c = 0; c < C; ++c) {
    float v = xp[(size_t)c * HW];
    accs = fmaf(sw[c], fmaxf(v, 0.f), accs);
    acc9 = fmaf(st[c], v, acc9);
  }
  t5[n * HW + p] = p4[p] * accs;
  t13[n * HW + p] = p13[p] * acc9;
}

// ---------------------------------------------------------------------------
// K3: per n: column maxima cm[ki][w'] of t5 (zero enters max when padding
//     exists, i.e. ki != 2), build t7[25][64], then t8 = W8 @ t7.
//     Grid: (n, o-quarter). cm/t7 recomputed per block (cheap).
// ---------------------------------------------------------------------------
__global__ __launch_bounds__(256) void k3_t8(
    const float* __restrict__ t5, const float* __restrict__ W8,
    float* __restrict__ t8) {
  int n = blockIdx.x >> 2;
  int og = (blockIdx.x & 3) << 6;
  int tid = threadIdx.x;
  __shared__ float s5[HW];
  __shared__ float cm[5][64];
  __shared__ float t7s[25][64];
  const float4* t5v = (const float4*)(t5 + n * HW);
  float4* s5v = (float4*)s5;
#pragma unroll
  for (int i = 0; i < 4; ++i) s5v[i * 256 + tid] = t5v[i * 256 + tid];
  __syncthreads();
  for (int idx = tid; idx < 5 * 64; idx += 256) {
    int ki = idx >> 6, wp = idx & 63;
    int lo = max(0, 3 * ki - 6), hi = min(63, 3 * ki + 57);
    float m = (ki == 2) ? -3.4e38f : 0.0f;  // pads contribute 0 to the max
    for (int hp = lo; hp <= hi; ++hp) m = fmaxf(m, s5[hp * 64 + wp]);
    cm[ki][wp] = m;
  }
  __syncthreads();
  for (int idx = tid; idx < 25 * 64; idx += 256) {
    int k = idx >> 6, w = idx & 63;
    int ki = k / 5, kj = k % 5;
    int wp = w + 3 * kj - 6;
    t7s[k][w] = (wp >= 0 && wp < 64) ? cm[ki][wp] : 0.0f;
  }
  __syncthreads();
  int w = tid & 63, orow = tid >> 6;
  for (int i = 0; i < 16; ++i) {
    int o = og + orow * 16 + i;
    float acc = 0.f;
#pragma unroll
    for (int k = 0; k < 25; ++k) acc = fmaf(W8[o * 25 + k], t7s[k][w], acc);
    t8[(n * C + o) * 64 + w] = acc;
  }
}

// ---------------------------------------------------------------------------
// K4: t10 = W10 @ t8 (per n), fused: t12 = t6resh + gelu(t10), reduce
//     max over the 100 o-rows of this block's tile -> part[n][tile][w].
//     t8[n] (64 KB) staged in LDS; 5-row register tile amortizes LDS reads.
// ---------------------------------------------------------------------------
__global__ __launch_bounds__(256) void k4_t10max(
    const float* __restrict__ t8, const float* __restrict__ W10,
    const float* __restrict__ t5, float* __restrict__ part) {
  int n = blockIdx.x >> 4;
  int tile = blockIdx.x & 15;
  int tid = threadIdx.x;
  int w = tid & 63, r = tid >> 6;
  __shared__ float t8s[C * 64];  // 64 KB
  const float4* t8v = (const float4*)(t8 + (size_t)n * C * 64);
  float4* t8sv = (float4*)t8s;
#pragma unroll
  for (int i = 0; i < 16; ++i) t8sv[i * 256 + tid] = t8v[i * 256 + tid];
  __syncthreads();
  const float4* w10v = (const float4*)W10;
  const float* t5n = t5 + n * HW;
  float pmax = -3.4e38f;
  int ob = tile * 100 + r * 25;
  for (int g = 0; g < 5; ++g) {
    int o0 = ob + g * 5;
    float acc[5] = {0.f, 0.f, 0.f, 0.f, 0.f};
    for (int c4 = 0; c4 < 64; ++c4) {
      float v0 = t8s[(c4 * 4 + 0) * 64 + w];
      float v1 = t8s[(c4 * 4 + 1) * 64 + w];
      float v2 = t8s[(c4 * 4 + 2) * 64 + w];
      float v3 = t8s[(c4 * 4 + 3) * 64 + w];
#pragma unroll
      for (int j = 0; j < 5; ++j) {
        float4 a = w10v[(o0 + j) * 64 + c4];
        acc[j] = fmaf(a.x, v0, fmaf(a.y, v1, fmaf(a.z, v2, fmaf(a.w, v3, acc[j]))));
      }
    }
#pragma unroll
    for (int j = 0; j < 5; ++j) {
      int o = o0 + j;
      int k = o >> 6, h = o & 63;
      int ki = k / 5, kj = k % 5;
      int hp = h + 3 * ki - 6, wp = w + 3 * kj - 6;
      float t6v = (hp >= 0 && hp < 64 && wp >= 0 && wp < 64)
                      ? t5n[hp * 64 + wp] : 0.0f;
      float xg = acc[j];
      float gl = 0.5f * xg * (1.0f + erff(xg * 0.70710678118654752f));
      pmax = fmaxf(pmax, t6v + gl);
    }
  }
  __syncthreads();           // everyone done with t8s — reuse as scratch
  float* red = t8s;
  red[r * 64 + w] = pmax;
  __syncthreads();
  if (r == 0) {
    float m = fmaxf(fmaxf(red[w], red[64 + w]), fmaxf(red[128 + w], red[192 + w]));
    part[(n * 16 + tile) * 64 + w] = m;
  }
}

// ---------------------------------------------------------------------------
// K5: M[n,w'] = exp(max over 16 tile partials); t17[n,w] = mean_j of valid M
// ---------------------------------------------------------------------------
__global__ __launch_bounds__(64) void k5_t17(
    const float* __restrict__ part, float* __restrict__ t17) {
  int n = blockIdx.x;
  int w = threadIdx.x;
  float m = -3.4e38f;
#pragma unroll
  for (int t = 0; t < 16; ++t) m = fmaxf(m, part[(n * 16 + t) * 64 + w]);
  __shared__ float M[64];
  M[w] = expf(m);
  __syncthreads();
  float s = 0.f;
#pragma unroll
  for (int j = 0; j < 7; ++j) {
    int wp = w + 3 * j - 9;
    if (wp >= 0 && wp < 64) s += M[wp];  // w-padding contributes 0
  }
  t17[n * 64 + w] = s * (1.0f / 7.0f);
}

// ---------------------------------------------------------------------------
// K6: out[n,c,h,w] = t13[n,h,w] - W18[c*64+h] * t17[n,w]   (128 MiB write)
// ---------------------------------------------------------------------------
__global__ __launch_bounds__(256) void k6_out(
    const float* __restrict__ t13, const float* __restrict__ t17,
    const float* __restrict__ W18, float* __restrict__ out) {
  int b = blockIdx.x;  // n*C + c
  int n = b >> 8, c = b & 255;
  int tid = threadIdx.x;
  const float4* t13v = (const float4*)(t13 + n * HW);
  const float4* t17v = (const float4*)(t17 + n * 64);
  float4* outv = (float4*)(out + (size_t)b * HW);
#pragma unroll
  for (int i = 0; i < 4; ++i) {
    int idx = i * 256 + tid;   // float4 index within the (h,w) plane
    int h = idx >> 4;          // (idx*4)/64
    int w4 = idx & 15;         // ((idx*4)%64)/4
    float w18 = W18[c * 64 + h];
    float4 a = t13v[idx];
    float4 tt = t17v[w4];
    float4 o;
    o.x = a.x - w18 * tt.x;
    o.y = a.y - w18 * tt.y;
    o.z = a.z - w18 * tt.z;
    o.w = a.w - w18 * tt.w;
    outv[idx] = o;
  }
}

// ---------------------------------------------------------------------------
extern "C" void kernel_launch(void* const* d_in, const int* in_sizes, int n_in,
                              void* d_out, int out_size, void* d_ws,
                              size_t ws_size, hipStream_t stream) {
  const float* x   = (const float*)d_in[0];
  const float* W2  = (const float*)d_in[1];
  const float* W8  = (const float*)d_in[2];
  const float* W10 = (const float*)d_in[3];
  const float* W18 = (const float*)d_in[4];
  const float* p4  = (const float*)d_in[5];
  const float* p13 = (const float*)d_in[6];
  float* out = (float*)d_out;

  float* ws    = (float*)d_ws;
  float* w2bar = ws;                  // 256
  float* t3    = w2bar + 256;         // 32*256
  float* t5    = t3 + NB * C;         // 32*4096
  float* t13   = t5 + NB * HW;        // 32*4096
  float* t8    = t13 + NB * HW;       // 32*256*64
  float* part  = t8 + NB * C * 64;    // 32*16*64
  float* t17   = part + NB * 16 * 64; // 32*64

  k1_t3_prep<<<dim3(NB * C + 1), dim3(256), 0, stream>>>(x, W2, w2bar, t3);
  k2_s_t9<<<dim3(NB * 16), dim3(256), 0, stream>>>(x, w2bar, t3, p4, p13, t5, t13);
  k3_t8<<<dim3(NB * 4), dim3(256), 0, stream>>>(t5, W8, t8);
  k4_t10max<<<dim3(NB * 16), dim3(256), 0, stream>>>(t8, W10, t5, part);
  k5_t17<<<dim3(NB), dim3(64), 0, stream>>>(part, t17);
  k6_out<<<dim3(NB * C), dim3(256), 0, stream>>>(t13, t17, W18, out);
}